// Round 15
// baseline (235.141 us; speedup 1.0000x reference)
//
#include <hip/hip_runtime.h>
#include <math.h>

#define BATCH  8
#define SEQLEN 4096
#define HID    1024
#define STATE  64
#define NC     16
#define TC     (SEQLEN / NC)   // 256 steps per chunk
#define TT     32              // time rows per LDS tile (k1/scalar path)
#define NTILE  (TC / TT)
#define DBLK   64
#define NS     16
#define NP     8
#define RB     8

typedef float f32x2 __attribute__((ext_vector_type(2)));
typedef float f32x4 __attribute__((ext_vector_type(4)));
typedef short bf16x8 __attribute__((ext_vector_type(8)));
typedef unsigned int u32x4 __attribute__((ext_vector_type(4)));

// ws layout (bytes)
#define WS_PA   0
#define WS_PW   (256 * 1024)
#define WS_PE   (512 * 1024)
#define WS_PL2  (768 * 1024)
#define WS_ZL   (1ull  * 1024 * 1024)   // f32 [15][8][1024][64] = 30 MB
#define WS_ZT   (36ull * 1024 * 1024)   // ushort[1024][128][64] = 16 MB
#define WS_W2F  (56ull * 1024 * 1024)   // ushort[1024][16384]   = 32 MB (fragment-major)
#define WS_KRF  (92ull * 1024 * 1024)   // ushort[1024][8192]    = 16 MB (fragment-major)
#define WS_NEED (148ull * 1024 * 1024)

__device__ __forceinline__ unsigned int f2bf(float x) {
    unsigned int u = __builtin_bit_cast(unsigned int, x);
    u = (u + 0x7FFFu + ((u >> 16) & 1u)) >> 16;
    return u & 0xFFFFu;
}

__device__ __forceinline__ void gload_lds16(const void* g, void* l) {
    __builtin_amdgcn_global_load_lds((const __attribute__((address_space(1))) void*)g,
                                     (__attribute__((address_space(3))) void*)l,
                                     16, 0, 0);
}

__device__ __forceinline__ float quad_reduce_add(float y) {
    int t = __builtin_amdgcn_mov_dpp(__builtin_bit_cast(int, y), 0xB1, 0xF, 0xF, true);
    y += __builtin_bit_cast(float, t);
    t = __builtin_amdgcn_mov_dpp(__builtin_bit_cast(int, y), 0x4E, 0xF, 0xF, true);
    y += __builtin_bit_cast(float, t);
    return y;
}

// ---------------------------------------------------------------- K0: params
__global__ void k0_params(const float* __restrict__ A, const float* __restrict__ Bm,
                          const float* __restrict__ C, const float* __restrict__ dt,
                          float* __restrict__ pa, float* __restrict__ pw,
                          float* __restrict__ pE, float* __restrict__ pl2) {
    int i = blockIdx.x * 256 + threadIdx.x;
    if (i >= HID * STATE) return;
    int n = i & (STATE - 1);
    float aexp = expf(A[i]);
    float dtn  = dt[n];
    float a    = expf(-aexp * dtn);
    pa[i]  = a;
    pw[i]  = C[i] * (Bm[i] * (1.0f - a) / aexp);
    pE[i]  = expf(-aexp * dtn * (float)TC);
    pl2[i] = -aexp * dtn * 1.44269504088896340736f;   // log2(a)
}

// ------------------------------------------- K1: chunk-local end states (r10-proven)
__global__ __launch_bounds__(256, 3) void k1_locals(const float* __restrict__ u,
                                                    const float* __restrict__ pa,
                                                    float* __restrict__ zl) {
    __shared__ float utile[2][TT * DBLK];
    int bid  = blockIdx.x;
    int dset = bid & 15;
    int b    = (bid >> 4) & 7;
    int c    = bid >> 7;                       // chunk 0..NC-2
    int w    = threadIdx.x >> 6;
    int lane = threadIdx.x & 63;
    int dl   = lane >> 2, p = lane & 3;
    int d    = dset * DBLK + w * 16 + dl;

    f32x2 a2[NP], z2[NP];
    {
        const f32x2* pap = (const f32x2*)(pa + (size_t)d * STATE + p * NS);
        #pragma unroll
        for (int j = 0; j < NP; j++) a2[j] = pap[j];
    }
    #pragma unroll
    for (int j = 0; j < NP; j++) { z2[j].x = 0.f; z2[j].y = 0.f; }

    const char* ubase = (const char*)(u + ((size_t)b * SEQLEN + (size_t)c * TC) * HID
                                        + (size_t)dset * DBLK);

    #define ISSUE_TILE(t, buf)                                                        \
        {                                                                             \
            _Pragma("unroll")                                                         \
            for (int k = 0; k < 2; k++) {                                             \
                int off = w * 2048 + k * 1024 + lane * 16;                            \
                int row = off >> 8;                                                   \
                int col = off & 255;                                                  \
                const float* src = (const float*)(ubase + ((size_t)((t) * TT + row)) * (HID * 4) + col); \
                float* dst = &utile[buf][w * 512 + k * 256];                           \
                gload_lds16(src, dst);                                                \
            }                                                                         \
        }

    ISSUE_TILE(0, 0);
    __syncthreads();
    int cur = 0;
    for (int tile = 0; tile < NTILE; ++tile) {
        if (tile + 1 < NTILE) ISSUE_TILE(tile + 1, cur ^ 1);
        const float* ut = &utile[cur][w * 16 + dl];
        #pragma unroll
        for (int r = 0; r < TT; r++) {
            float uss = ut[r * DBLK];
            f32x2 us; us.x = uss; us.y = uss;
            #pragma unroll
            for (int j = 0; j < NP; j++)
                z2[j] = __builtin_elementwise_fma(a2[j], z2[j], us);
        }
        __syncthreads();
        cur ^= 1;
    }

    f32x2* zp = (f32x2*)(zl + (((size_t)c * BATCH + b) * HID + d) * STATE + p * NS);
    #pragma unroll
    for (int j = 0; j < NP; j++) zp[j] = z2[j];
}

// ---------------------------------- K2 (fallback): prefix scan in-place in zl
__global__ void k2_scan(const float* __restrict__ pE, float* __restrict__ zl) {
    int i  = blockIdx.x * 256 + threadIdx.x;
    int dn = i & (HID * STATE - 1);
    float E = pE[dn];
    size_t stride = (size_t)BATCH * HID * STATE;
    float g = zl[i];
    for (int c = 1; c < NC - 1; c++) {
        float v = zl[i + c * stride];
        g = fmaf(E, g, v);
        zl[i + c * stride] = g;
    }
}

// ---------------------------------- K2-ZT (mfma): scan + emit bf16 chunk-inits
__global__ void k2_zt(const float* __restrict__ pE, const float* __restrict__ zl,
                      unsigned short* __restrict__ ZT) {
    int i = blockIdx.x * 256 + threadIdx.x;     // b*65536 + d*64 + n
    int n = i & 63;
    int d = (i >> 6) & 1023;
    int b = i >> 16;
    float E = pE[d * 64 + n];
    size_t stride = (size_t)BATCH * HID * STATE;
    unsigned short* zt = ZT + (size_t)d * 8192 + (size_t)b * 1024 + n;
    zt[0] = 0;                                   // c=0 init state = 0
    float g = zl[i];                             // end of chunk 0
    zt[64] = (unsigned short)f2bf(g);            // c=1 init
    for (int c = 2; c < 16; c++) {
        g = fmaf(E, g, zl[i + (size_t)(c - 1) * stride]);
        zt[(size_t)c * 64] = (unsigned short)f2bf(g);
    }
}

// ---------------------------------- kKRF: fragment-major conv-kernel table
// KRF[d][m][lane l][j] = K_d[x], x = r16 - 8g + 16m - j (0 if x<0); K(0) += Dv.
__global__ void k_krf(const float* __restrict__ pw, const float* __restrict__ pl2,
                      const float* __restrict__ Dv, unsigned short* __restrict__ KRF) {
    __shared__ float wv[64], e2[64], K[256];
    int d = blockIdx.x, t = threadIdx.x;         // 256 threads
    if (t < 64) { wv[t] = pw[d * 64 + t]; e2[t] = pl2[d * 64 + t]; }
    __syncthreads();
    float s = 0.0f;
    for (int n = 0; n < 64; n++) s += wv[n] * exp2f((float)t * e2[n]);
    if (t == 0) s += Dv[d];
    K[t] = s;
    __syncthreads();
    for (int idx = t; idx < 8192; idx += 256) {
        int j  = idx & 7;
        int ll = (idx >> 3) & 63;
        int m  = idx >> 9;
        int x  = (ll & 15) - 8 * (ll >> 4) + 16 * m - j;
        unsigned short v = 0;
        if (x >= 0) v = (unsigned short)f2bf(K[x]);
        KRF[(size_t)d * 8192 + idx] = v;
    }
}

// ---------------------------------- kW2F: fragment-major state-correction table
__global__ void k_w2f(const float* __restrict__ pw, const float* __restrict__ pl2,
                      unsigned short* __restrict__ W2F) {
    __shared__ float wv[64], e2[64];
    int d = blockIdx.x, t = threadIdx.x;
    if (t < 64) { wv[t] = pw[d * 64 + t]; e2[t] = pl2[d * 64 + t]; }
    __syncthreads();
    for (int idx = t; idx < 16384; idx += 256) {
        int j  = idx & 7;
        int ll = (idx >> 3) & 63;
        int ns = (idx >> 9) & 1;
        int tt = idx >> 10;
        int n  = ns * 32 + 8 * (ll >> 4) + j;
        int tg = tt * 16 + (ll & 15);
        float val = wv[n] * exp2f((float)(tg + 1) * e2[n]);
        W2F[(size_t)d * 16384 + idx] = (unsigned short)f2bf(val);
    }
}

// ---------------------------------- K3 MFMA: 64KB tile, 2 blocks/CU, 1 wave = 1 d
// block: 8 d x 16 bc x 256 s. 512 thr = 8 waves. dg-pairs co-XCD so the two
// half-line (32B) u reads / out writes merge in that XCD's L2.
__global__ __launch_bounds__(512, 4) void k3_mfma(const float* __restrict__ u,
                                                  const unsigned short* __restrict__ KRF,
                                                  const unsigned short* __restrict__ W2F,
                                                  const unsigned short* __restrict__ ZT,
                                                  float* __restrict__ out) {
    __shared__ __align__(16) char smem[65536];   // [dloc8][bc16][32 slots x 16B]
    int bid = blockIdx.x;
    int qx  = bid & 7;                  // XCD
    int r   = bid >> 3;
    int p   = r & 15;
    int bcg = r >> 4;                   // 0..7
    int dg  = (((p & 7) * 8 + qx) << 1) | (p >> 3);   // 0..127; dg-pairs share qx
    int tid = threadIdx.x;
    int w   = tid >> 6;                 // wave 0..7, owns d = dg*8 + w
    int l   = tid & 63;
    int g   = l >> 4, r16 = l & 15;
    int d   = dg * 8 + w;

    // ---- stage u (f32, dwordx4 over d) -> bf16 LDS, swizzled slots
    {
        int dq = tid & 1;               // d-quad 0/1
        int bc = (tid >> 1) & 15;
        int sg = tid >> 5;              // 0..15, s in [sg*16, sg*16+16)
        int gbc = bcg * 16 + bc;
        int bs = gbc >> 4, cs = gbc & 15;
        const f32x4* up = (const f32x4*)(u + ((size_t)(bs * SEQLEN + cs * TC + sg * 16)) * HID
                                           + dg * 8 + dq * 4);
        #pragma unroll
        for (int half = 0; half < 2; half++) {
            f32x4 v[8];
            #pragma unroll
            for (int j = 0; j < 8; j++) v[j] = up[(size_t)(half * 8 + j) * 256];
            #pragma unroll
            for (int dd = 0; dd < 4; dd++) {
                unsigned int pk[4];
                #pragma unroll
                for (int q = 0; q < 4; q++)
                    pk[q] = f2bf(v[2 * q][dd]) | (f2bf(v[2 * q + 1][dd]) << 16);
                int dloc = dq * 4 + dd;
                int sc   = sg * 2 + half;
                int slot = (sc + 5 * bc + 3 * dloc) & 31;
                *(u32x4*)(&smem[(unsigned)((dloc * 16 + bc) * 512) + slot * 16]) =
                    (u32x4){pk[0], pk[1], pk[2], pk[3]};
            }
        }
    }
    __syncthreads();

    f32x4 acc[16];
    #pragma unroll
    for (int tt = 0; tt < 16; tt++) acc[tt] = (f32x4){0.f, 0.f, 0.f, 0.f};

    const unsigned short* krf = KRF + (size_t)d * 8192 + l * 8;
    unsigned int rowr = (unsigned)(w * 16 + r16) * 512;
    int rot = (5 * r16 + 3 * w) & 31;

    // ---- conv core, half 1: m = 0..7
    {
        bf16x8 Af[8];
        #pragma unroll
        for (int mm = 0; mm < 8; mm++)
            Af[mm] = *(const bf16x8*)(krf + (size_t)mm * 512);
        #pragma unroll
        for (int mm = 0; mm < 8; mm++) {
            #pragma unroll
            for (int sk = 0; sk < 8; sk++) {
                if (2 * sk + mm <= 15) {
                    int slot = ((sk * 4 + g) + rot) & 31;
                    bf16x8 B = *(const bf16x8*)(&smem[rowr + slot * 16]);
                    acc[2 * sk + mm] =
                        __builtin_amdgcn_mfma_f32_16x16x32_bf16(Af[mm], B, acc[2 * sk + mm], 0, 0, 0);
                }
            }
        }
    }
    __builtin_amdgcn_sched_barrier(0);
    // ---- conv core, half 2: m = 8..15
    {
        bf16x8 Af[8];
        #pragma unroll
        for (int mm = 0; mm < 8; mm++)
            Af[mm] = *(const bf16x8*)(krf + (size_t)(8 + mm) * 512);
        #pragma unroll
        for (int mm = 0; mm < 8; mm++) {
            #pragma unroll
            for (int sk = 0; sk < 4; sk++) {
                if (2 * sk + 8 + mm <= 15) {
                    int slot = ((sk * 4 + g) + rot) & 31;
                    bf16x8 B = *(const bf16x8*)(&smem[rowr + slot * 16]);
                    acc[2 * sk + 8 + mm] =
                        __builtin_amdgcn_mfma_f32_16x16x32_bf16(Af[mm], B, acc[2 * sk + 8 + mm], 0, 0, 0);
                }
            }
        }
    }
    __builtin_amdgcn_sched_barrier(0);

    // ---- state-init correction: acc[tt] += W2F(tt,ns) x ZT(bc,n)
    {
        const unsigned short* ztd = ZT + (size_t)d * 8192 + (size_t)bcg * 1024;
        bf16x8 Bz0 = *(const bf16x8*)(ztd + (size_t)r16 * 64 + 0 * 32 + 8 * g);
        bf16x8 Bz1 = *(const bf16x8*)(ztd + (size_t)r16 * 64 + 1 * 32 + 8 * g);
        const unsigned short* w2f = W2F + (size_t)d * 16384 + l * 8;
        #pragma unroll
        for (int grp = 0; grp < 4; grp++) {
            bf16x8 Aw[8];
            #pragma unroll
            for (int q = 0; q < 8; q++) {
                int tt = grp * 4 + (q >> 1);
                int ns = q & 1;
                Aw[q] = *(const bf16x8*)(w2f + (size_t)(tt * 2 + ns) * 512);
            }
            #pragma unroll
            for (int q = 0; q < 8; q++) {
                int tt = grp * 4 + (q >> 1);
                acc[tt] = __builtin_amdgcn_mfma_f32_16x16x32_bf16(Aw[q], (q & 1) ? Bz1 : Bz0,
                                                                  acc[tt], 0, 0, 0);
            }
            __builtin_amdgcn_sched_barrier(0);
        }
    }

    // ---- epilogue: padded LDS transpose (strides 147/9) -> 32B stores, L2-merged
    float* eps = (float*)smem;
    int dhalf = tid & 1;
    int bcr   = (tid >> 1) & 15;
    int t16r  = tid >> 5;               // 0..15
    int gbcr  = bcg * 16 + bcr;
    int bo = gbcr >> 4, co = gbcr & 15;
    float* pout = out + ((size_t)(bo * SEQLEN + co * TC + t16r)) * HID + dg * 8 + dhalf * 4;
    #pragma unroll
    for (int tt = 0; tt < 16; tt++) {
        __syncthreads();
        #pragma unroll
        for (int rr = 0; rr < 4; rr++)
            eps[(4 * g + rr) * 147 + r16 * 9 + w] = acc[tt][rr];
        __syncthreads();
        f32x4 vv;
        #pragma unroll
        for (int j = 0; j < 4; j++) vv[j] = eps[t16r * 147 + bcr * 9 + dhalf * 4 + j];
        *(f32x4*)(pout + (size_t)(tt * 16) * HID) = vv;
    }
}

// ---------------------------------- fallback scalar K3 (round-10 best, 118 us)
__global__ __launch_bounds__(256, 3) void k3_scalar(const float* __restrict__ u,
                                                    const float* __restrict__ Dv,
                                                    const float* __restrict__ pa,
                                                    const float* __restrict__ pw,
                                                    const float* __restrict__ zl,
                                                    float* __restrict__ out) {
    __shared__ float utile[2][TT * DBLK];
    int bid  = blockIdx.x;
    int dset = bid & 15;
    int b    = (bid >> 4) & 7;
    int c    = bid >> 7;
    int w    = threadIdx.x >> 6;
    int lane = threadIdx.x & 63;
    int dl   = lane >> 2, p = lane & 3;
    int d    = dset * DBLK + w * 16 + dl;

    f32x2 a2[NP], w2[NP], z2[NP];
    {
        const f32x2* pap = (const f32x2*)(pa + (size_t)d * STATE + p * NS);
        const f32x2* pwp = (const f32x2*)(pw + (size_t)d * STATE + p * NS);
        #pragma unroll
        for (int j = 0; j < NP; j++) { a2[j] = pap[j]; w2[j] = pwp[j]; }
    }
    if (c == 0) {
        #pragma unroll
        for (int j = 0; j < NP; j++) { z2[j].x = 0.f; z2[j].y = 0.f; }
    } else {
        size_t stride = (size_t)BATCH * HID * STATE;
        const f32x2* zp = (const f32x2*)(zl + (size_t)(c - 1) * stride +
                                         ((size_t)b * HID + d) * STATE + p * NS);
        #pragma unroll
        for (int j = 0; j < NP; j++) z2[j] = zp[j];
    }

    float dvd = Dv[d];
    const char* ubase = (const char*)(u + ((size_t)b * SEQLEN + (size_t)c * TC) * HID
                                        + (size_t)dset * DBLK);
    float* po = out + ((size_t)b * SEQLEN + (size_t)c * TC) * HID + d;

    ISSUE_TILE(0, 0);
    __syncthreads();
    int cur = 0;
    for (int tile = 0; tile < NTILE; ++tile) {
        if (tile + 1 < NTILE) ISSUE_TILE(tile + 1, cur ^ 1);
        const float* ut = &utile[cur][w * 16 + dl];
        float* po_t = po + (size_t)tile * TT * HID;
        #pragma unroll
        for (int r0 = 0; r0 < TT; r0 += RB) {
            float ylane[RB], usv[RB];
            #pragma unroll
            for (int i = 0; i < RB; i++) {
                float uss = ut[(r0 + i) * DBLK];
                usv[i] = uss;
                f32x2 us; us.x = uss; us.y = uss;
                #pragma unroll
                for (int j = 0; j < NP; j++)
                    z2[j] = __builtin_elementwise_fma(a2[j], z2[j], us);
                f32x2 acc0 = z2[0] * w2[0];
                f32x2 acc1 = z2[1] * w2[1];
                #pragma unroll
                for (int j = 2; j < NP; j += 2) {
                    acc0 = __builtin_elementwise_fma(z2[j + 0], w2[j + 0], acc0);
                    acc1 = __builtin_elementwise_fma(z2[j + 1], w2[j + 1], acc1);
                }
                acc0 += acc1;
                ylane[i] = acc0.x + acc0.y;
            }
            #pragma unroll
            for (int i = 0; i < RB; i++) ylane[i] = quad_reduce_add(ylane[i]);
            #pragma unroll
            for (int i = 0; i < RB; i++)
                po_t[(size_t)(r0 + i) * HID] = fmaf(dvd, usv[i], ylane[i]);
        }
        __syncthreads();
        cur ^= 1;
    }
}

extern "C" void kernel_launch(void* const* d_in, const int* in_sizes, int n_in,
                              void* d_out, int out_size, void* d_ws, size_t ws_size,
                              hipStream_t stream) {
    const float* u  = (const float*)d_in[0];
    const float* A  = (const float*)d_in[1];
    const float* Bm = (const float*)d_in[2];
    const float* C  = (const float*)d_in[3];
    const float* Dv = (const float*)d_in[4];
    const float* dt = (const float*)d_in[5];
    float* out = (float*)d_out;

    char* ws = (char*)d_ws;
    float* pa  = (float*)(ws + WS_PA);
    float* pw  = (float*)(ws + WS_PW);
    float* pE  = (float*)(ws + WS_PE);
    float* pl2 = (float*)(ws + WS_PL2);
    float* zl  = (float*)(ws + WS_ZL);
    unsigned short* ZT  = (unsigned short*)(ws + WS_ZT);
    unsigned short* W2F = (unsigned short*)(ws + WS_W2F);
    unsigned short* KRF = (unsigned short*)(ws + WS_KRF);

    bool mfma = (ws_size >= WS_NEED);

    k0_params<<<(HID * STATE) / 256, 256, 0, stream>>>(A, Bm, C, dt, pa, pw, pE, pl2);
    k1_locals<<<16 * 8 * (NC - 1), 256, 0, stream>>>(u, pa, zl);

    if (mfma) {
        k_krf<<<1024, 256, 0, stream>>>(pw, pl2, Dv, KRF);
        k_w2f<<<1024, 256, 0, stream>>>(pw, pl2, W2F);
        k2_zt<<<(BATCH * HID * STATE) / 256, 256, 0, stream>>>(pE, zl, ZT);
        k3_mfma<<<1024, 512, 0, stream>>>(u, KRF, W2F, ZT, out);
    } else {
        k2_scan<<<(BATCH * HID * STATE) / 256, 256, 0, stream>>>(pE, zl);
        k3_scalar<<<16 * 8 * NC, 256, 0, stream>>>(u, Dv, pa, pw, zl, out);
    }
}

// Round 17
// 162.230 us; speedup vs baseline: 1.4494x; 1.4494x over previous
//
#include <hip/hip_runtime.h>
#include <math.h>

#define BATCH  8
#define SEQLEN 4096
#define HID    1024
#define STATE  64
#define NC     16
#define TC     (SEQLEN / NC)   // 256 steps per chunk
#define TT     32              // time rows per LDS tile (k1/scalar path)
#define NTILE  (TC / TT)
#define DBLK   64
#define NS     16
#define NP     8
#define RB     8

typedef float f32x2 __attribute__((ext_vector_type(2)));
typedef float f32x4 __attribute__((ext_vector_type(4)));
typedef short bf16x8 __attribute__((ext_vector_type(8)));
typedef unsigned int u32x4 __attribute__((ext_vector_type(4)));

// ws layout (bytes). NOTE: KRF overlays zl — zl is dead after k2_zt, and
// k_krf launches AFTER k2_zt. No other overlaps (audited):
//   params [0,1M) | zl [1M,31M) | KRF [1M,17M) after-zl | W2F [31M,63M)
//   | ZT [63M,79M) | UBF [79M,143M)
#define WS_PA   0
#define WS_PW   (256 * 1024)
#define WS_PE   (512 * 1024)
#define WS_PL2  (768 * 1024)
#define WS_ZL   (1ull  * 1024 * 1024)   // f32 [15][8][1024][64] = 30 MB
#define WS_KRF  (1ull  * 1024 * 1024)   // ushort[1024][8192] = 16 MB (after zl dead)
#define WS_W2F  (31ull * 1024 * 1024)   // ushort[1024][16384] = 32 MB
#define WS_ZT   (63ull * 1024 * 1024)   // ushort[1024][128][64] = 16 MB
#define WS_UBF  (79ull * 1024 * 1024)   // [gbc128][tile8][d1024][64B] = 64 MB
#define WS_NEED (143ull * 1024 * 1024)

__device__ __forceinline__ unsigned int f2bf(float x) {
    unsigned int u = __builtin_bit_cast(unsigned int, x);
    u = (u + 0x7FFFu + ((u >> 16) & 1u)) >> 16;
    return u & 0xFFFFu;
}

__device__ __forceinline__ void gload_lds16(const void* g, void* l) {
    __builtin_amdgcn_global_load_lds((const __attribute__((address_space(1))) void*)g,
                                     (__attribute__((address_space(3))) void*)l,
                                     16, 0, 0);
}

__device__ __forceinline__ float quad_reduce_add(float y) {
    int t = __builtin_amdgcn_mov_dpp(__builtin_bit_cast(int, y), 0xB1, 0xF, 0xF, true);
    y += __builtin_bit_cast(float, t);
    t = __builtin_amdgcn_mov_dpp(__builtin_bit_cast(int, y), 0x4E, 0xF, 0xF, true);
    y += __builtin_bit_cast(float, t);
    return y;
}

// ---------------------------------------------------------------- K0: params
__global__ void k0_params(const float* __restrict__ A, const float* __restrict__ Bm,
                          const float* __restrict__ C, const float* __restrict__ dt,
                          float* __restrict__ pa, float* __restrict__ pw,
                          float* __restrict__ pE, float* __restrict__ pl2) {
    int i = blockIdx.x * 256 + threadIdx.x;
    if (i >= HID * STATE) return;
    int n = i & (STATE - 1);
    float aexp = expf(A[i]);
    float dtn  = dt[n];
    float a    = expf(-aexp * dtn);
    pa[i]  = a;
    pw[i]  = C[i] * (Bm[i] * (1.0f - a) / aexp);
    pE[i]  = expf(-aexp * dtn * (float)TC);
    pl2[i] = -aexp * dtn * 1.44269504088896340736f;   // log2(a)
}

// ------------------------------------------- K1: chunk-local end states + UBF emit
__global__ __launch_bounds__(256, 3) void k1_locals(const float* __restrict__ u,
                                                    const float* __restrict__ pa,
                                                    float* __restrict__ zl,
                                                    unsigned short* __restrict__ ubf) {
    __shared__ float utile[2][TT * DBLK];
    __shared__ unsigned int lds_pk[64 * 17];
    int bid  = blockIdx.x;
    int dset = bid & 15;
    int b    = (bid >> 4) & 7;
    int c    = bid >> 7;                       // chunk 0..15 (mfma) / 0..14 (fallback)
    int w    = threadIdx.x >> 6;
    int lane = threadIdx.x & 63;
    int dl   = lane >> 2, p = lane & 3;
    int d    = dset * DBLK + w * 16 + dl;

    f32x2 a2[NP], z2[NP];
    {
        const f32x2* pap = (const f32x2*)(pa + (size_t)d * STATE + p * NS);
        #pragma unroll
        for (int j = 0; j < NP; j++) a2[j] = pap[j];
    }
    #pragma unroll
    for (int j = 0; j < NP; j++) { z2[j].x = 0.f; z2[j].y = 0.f; }

    const char* ubase = (const char*)(u + ((size_t)b * SEQLEN + (size_t)c * TC) * HID
                                        + (size_t)dset * DBLK);

    #define ISSUE_TILE(t, buf)                                                        \
        {                                                                             \
            _Pragma("unroll")                                                         \
            for (int k = 0; k < 2; k++) {                                             \
                int off = w * 2048 + k * 1024 + lane * 16;                            \
                int row = off >> 8;                                                   \
                int col = off & 255;                                                  \
                const float* src = (const float*)(ubase + ((size_t)((t) * TT + row)) * (HID * 4) + col); \
                float* dst = &utile[buf][w * 512 + k * 256];                           \
                gload_lds16(src, dst);                                                \
            }                                                                         \
        }

    ISSUE_TILE(0, 0);
    __syncthreads();
    int cur = 0;
    for (int tile = 0; tile < NTILE; ++tile) {
        if (tile + 1 < NTILE) ISSUE_TILE(tile + 1, cur ^ 1);
        const float* ut = &utile[cur][w * 16 + dl];
        #pragma unroll
        for (int r = 0; r < TT; r++) {
            float uss = ut[r * DBLK];
            f32x2 us; us.x = uss; us.y = uss;
            #pragma unroll
            for (int j = 0; j < NP; j++)
                z2[j] = __builtin_elementwise_fma(a2[j], z2[j], us);
        }
        if (ubf != nullptr) {
            // pack: wave w owns cols [w*16,+16); lane: col=w*16+(l&15), tgrp=l>>4
            int cw   = w * 16 + (lane & 15);
            int tgrp = lane >> 4;
            const float* colp = &utile[cur][cw];
            #pragma unroll
            for (int q = 0; q < 4; q++) {
                int r0 = tgrp * 8 + 2 * q;
                unsigned int pk = f2bf(colp[r0 * DBLK]) | (f2bf(colp[(r0 + 1) * DBLK]) << 16);
                lds_pk[cw * 17 + tgrp * 4 + q] = pk;
            }
            __syncthreads();
            // readout: linear 4KB store, thread tid -> 16B
            int dcol = threadIdx.x >> 2, jj = threadIdx.x & 3;
            u32x4 vv;
            #pragma unroll
            for (int k = 0; k < 4; k++) vv[k] = lds_pk[dcol * 17 + jj * 4 + k];
            unsigned short* dst = ubf + ((((size_t)(b * 16 + c) * 8 + tile) * 1024
                                          + dset * 64) * 32);   // *64B / 2B
            *(u32x4*)((char*)dst + threadIdx.x * 16) = vv;
        }
        __syncthreads();
        cur ^= 1;
    }

    if (c < NC - 1) {
        f32x2* zp = (f32x2*)(zl + (((size_t)c * BATCH + b) * HID + d) * STATE + p * NS);
        #pragma unroll
        for (int j = 0; j < NP; j++) zp[j] = z2[j];
    }
}

// ---------------------------------- K2 (fallback): prefix scan in-place in zl
__global__ void k2_scan(const float* __restrict__ pE, float* __restrict__ zl) {
    int i  = blockIdx.x * 256 + threadIdx.x;
    int dn = i & (HID * STATE - 1);
    float E = pE[dn];
    size_t stride = (size_t)BATCH * HID * STATE;
    float g = zl[i];
    for (int c = 1; c < NC - 1; c++) {
        float v = zl[i + c * stride];
        g = fmaf(E, g, v);
        zl[i + c * stride] = g;
    }
}

// ---------------------------------- K2-ZT (mfma): scan + emit bf16 chunk-inits
__global__ void k2_zt(const float* __restrict__ pE, const float* __restrict__ zl,
                      unsigned short* __restrict__ ZT) {
    int i = blockIdx.x * 256 + threadIdx.x;     // b*65536 + d*64 + n
    int n = i & 63;
    int d = (i >> 6) & 1023;
    int b = i >> 16;
    float E = pE[d * 64 + n];
    size_t stride = (size_t)BATCH * HID * STATE;
    unsigned short* zt = ZT + (size_t)d * 8192 + (size_t)b * 1024 + n;
    zt[0] = 0;
    float g = zl[i];
    zt[64] = (unsigned short)f2bf(g);
    for (int c = 2; c < 16; c++) {
        g = fmaf(E, g, zl[i + (size_t)(c - 1) * stride]);
        zt[(size_t)c * 64] = (unsigned short)f2bf(g);
    }
}

// ---------------------------------- kKRF: fragment-major conv-kernel table
// (launched AFTER k2_zt: overlays the then-dead zl region)
__global__ void k_krf(const float* __restrict__ pw, const float* __restrict__ pl2,
                      const float* __restrict__ Dv, unsigned short* __restrict__ KRF) {
    __shared__ float wv[64], e2[64], K[256];
    int d = blockIdx.x, t = threadIdx.x;
    if (t < 64) { wv[t] = pw[d * 64 + t]; e2[t] = pl2[d * 64 + t]; }
    __syncthreads();
    float s = 0.0f;
    for (int n = 0; n < 64; n++) s += wv[n] * exp2f((float)t * e2[n]);
    if (t == 0) s += Dv[d];
    K[t] = s;
    __syncthreads();
    for (int idx = t; idx < 8192; idx += 256) {
        int j  = idx & 7;
        int ll = (idx >> 3) & 63;
        int m  = idx >> 9;
        int x  = (ll & 15) - 8 * (ll >> 4) + 16 * m - j;
        unsigned short v = 0;
        if (x >= 0) v = (unsigned short)f2bf(K[x]);
        KRF[(size_t)d * 8192 + idx] = v;
    }
}

// ---------------------------------- kW2F: fragment-major state-correction table
__global__ void k_w2f(const float* __restrict__ pw, const float* __restrict__ pl2,
                      unsigned short* __restrict__ W2F) {
    __shared__ float wv[64], e2[64];
    int d = blockIdx.x, t = threadIdx.x;
    if (t < 64) { wv[t] = pw[d * 64 + t]; e2[t] = pl2[d * 64 + t]; }
    __syncthreads();
    for (int idx = t; idx < 16384; idx += 256) {
        int j  = idx & 7;
        int ll = (idx >> 3) & 63;
        int ns = (idx >> 9) & 1;
        int tt = idx >> 10;
        int n  = ns * 32 + 8 * (ll >> 4) + j;
        int tg = tt * 16 + (ll & 15);
        float val = wv[n] * exp2f((float)(tg + 1) * e2[n]);
        W2F[(size_t)d * 16384 + idx] = (unsigned short)f2bf(val);
    }
}

// ---------------------------------- K3 MFMA: 128KB tile from UBF, 1 wave = 1 d
__global__ __launch_bounds__(1024, 1) void k3_mfma(const unsigned short* __restrict__ ubf,
                                                   const unsigned short* __restrict__ KRF,
                                                   const unsigned short* __restrict__ W2F,
                                                   const unsigned short* __restrict__ ZT,
                                                   float* __restrict__ out) {
    __shared__ __align__(16) char smem[131072];   // [dl16][bc16][32 slots x 16B]
    int bid = blockIdx.x;
    int dg  = bid & 63;          // xcd = bid%8 = dg%8 -> same-dg blocks share one L2
    int bcg = bid >> 6;          // 0..7
    int tid = threadIdx.x;
    int w   = tid >> 6;          // wave 0..15, owns d = dg*16 + w (stages dloc = w)
    int l   = tid & 63;
    int g   = l >> 4, r16 = l & 15;
    int d   = dg * 16 + w;

    // ---- stage: global_load_lds from UBF, source-side slot pre-swizzle
    {
        int h = l >> 5, q = l & 31;
        #pragma unroll
        for (int i = 0; i < 8; i++) {
            int bc = 2 * i + h;
            int sc = (q - 5 * bc - 3 * w) & 31;
            int gbc = bcg * 16 + bc;
            const char* src = (const char*)ubf
                + (((size_t)(gbc * 8 + (sc >> 2)) * 1024) + dg * 16 + w) * 64
                + (sc & 3) * 16;
            char* dst = &smem[(unsigned)(w * 16 + 2 * i) * 512];
            gload_lds16(src, dst);
        }
    }
    __syncthreads();

    f32x4 acc[16];
    #pragma unroll
    for (int tt = 0; tt < 16; tt++) acc[tt] = (f32x4){0.f, 0.f, 0.f, 0.f};

    const unsigned short* krf = KRF + (size_t)d * 8192 + l * 8;
    unsigned int rowr = (unsigned int)(w * 16 + r16) * 512;
    int rot = (5 * r16 + 3 * w) & 31;

    // ---- conv core, half 1: m = 0..7 (verified r14 structure)
    {
        bf16x8 Af[8];
        #pragma unroll
        for (int mm = 0; mm < 8; mm++)
            Af[mm] = *(const bf16x8*)(krf + (size_t)mm * 512);
        #pragma unroll
        for (int mm = 0; mm < 8; mm++) {
            #pragma unroll
            for (int sk = 0; sk < 8; sk++) {
                if (2 * sk + mm <= 15) {
                    int slot = ((sk * 4 + g) + rot) & 31;
                    bf16x8 B = *(const bf16x8*)(&smem[rowr + slot * 16]);
                    acc[2 * sk + mm] =
                        __builtin_amdgcn_mfma_f32_16x16x32_bf16(Af[mm], B, acc[2 * sk + mm], 0, 0, 0);
                }
            }
        }
    }
    __builtin_amdgcn_sched_barrier(0);
    // ---- conv core, half 2: m = 8..15
    {
        bf16x8 Af[8];
        #pragma unroll
        for (int mm = 0; mm < 8; mm++)
            Af[mm] = *(const bf16x8*)(krf + (size_t)(8 + mm) * 512);
        #pragma unroll
        for (int mm = 0; mm < 8; mm++) {
            #pragma unroll
            for (int sk = 0; sk < 4; sk++) {
                if (2 * sk + 8 + mm <= 15) {
                    int slot = ((sk * 4 + g) + rot) & 31;
                    bf16x8 B = *(const bf16x8*)(&smem[rowr + slot * 16]);
                    acc[2 * sk + 8 + mm] =
                        __builtin_amdgcn_mfma_f32_16x16x32_bf16(Af[mm], B, acc[2 * sk + 8 + mm], 0, 0, 0);
                }
            }
        }
    }
    __builtin_amdgcn_sched_barrier(0);

    // ---- state-init correction: acc[tt] += W2F(tt,ns) x ZT(bc,n)
    {
        const unsigned short* ztd = ZT + (size_t)d * 8192 + (size_t)bcg * 1024;
        bf16x8 Bz0 = *(const bf16x8*)(ztd + (size_t)r16 * 64 + 0 * 32 + 8 * g);
        bf16x8 Bz1 = *(const bf16x8*)(ztd + (size_t)r16 * 64 + 1 * 32 + 8 * g);
        const unsigned short* w2f = W2F + (size_t)d * 16384 + l * 8;
        #pragma unroll
        for (int grp = 0; grp < 4; grp++) {
            bf16x8 Aw[8];
            #pragma unroll
            for (int q = 0; q < 8; q++) {
                int tt = grp * 4 + (q >> 1);
                int ns = q & 1;
                Aw[q] = *(const bf16x8*)(w2f + (size_t)(tt * 2 + ns) * 512);
            }
            #pragma unroll
            for (int q = 0; q < 8; q++) {
                int tt = grp * 4 + (q >> 1);
                acc[tt] = __builtin_amdgcn_mfma_f32_16x16x32_bf16(Aw[q], (q & 1) ? Bz1 : Bz0,
                                                                  acc[tt], 0, 0, 0);
            }
            __builtin_amdgcn_sched_barrier(0);
        }
    }

    // ---- epilogue: padded LDS transpose -> full 64B-line stores (r14 verified)
    float* eps = (float*)smem;
    int p = tid >> 2, sub = tid & 3;
    int t16r = p >> 4, bcr = p & 15;
    int gbcr = bcg * 16 + bcr;
    int bo = gbcr >> 4, co = gbcr & 15;
    float* pout = out + ((size_t)(bo * SEQLEN + co * TC + t16r)) * HID + dg * 16 + sub * 4;
    #pragma unroll
    for (int tt = 0; tt < 16; tt++) {
        __syncthreads();
        #pragma unroll
        for (int rr = 0; rr < 4; rr++)
            eps[((g * 4 + rr) * 16 + r16) * 21 + w] = acc[tt][rr];
        __syncthreads();
        f32x4 vv;
        #pragma unroll
        for (int j = 0; j < 4; j++) vv[j] = eps[p * 21 + sub * 4 + j];
        *(f32x4*)(pout + (size_t)(tt * 16) * HID) = vv;
    }
}

// ---------------------------------- fallback scalar K3 (round-10 best, 118 us)
__global__ __launch_bounds__(256, 3) void k3_scalar(const float* __restrict__ u,
                                                    const float* __restrict__ Dv,
                                                    const float* __restrict__ pa,
                                                    const float* __restrict__ pw,
                                                    const float* __restrict__ zl,
                                                    float* __restrict__ out) {
    __shared__ float utile[2][TT * DBLK];
    int bid  = blockIdx.x;
    int dset = bid & 15;
    int b    = (bid >> 4) & 7;
    int c    = bid >> 7;
    int w    = threadIdx.x >> 6;
    int lane = threadIdx.x & 63;
    int dl   = lane >> 2, p = lane & 3;
    int d    = dset * DBLK + w * 16 + dl;

    f32x2 a2[NP], w2[NP], z2[NP];
    {
        const f32x2* pap = (const f32x2*)(pa + (size_t)d * STATE + p * NS);
        const f32x2* pwp = (const f32x2*)(pw + (size_t)d * STATE + p * NS);
        #pragma unroll
        for (int j = 0; j < NP; j++) { a2[j] = pap[j]; w2[j] = pwp[j]; }
    }
    if (c == 0) {
        #pragma unroll
        for (int j = 0; j < NP; j++) { z2[j].x = 0.f; z2[j].y = 0.f; }
    } else {
        size_t stride = (size_t)BATCH * HID * STATE;
        const f32x2* zp = (const f32x2*)(zl + (size_t)(c - 1) * stride +
                                         ((size_t)b * HID + d) * STATE + p * NS);
        #pragma unroll
        for (int j = 0; j < NP; j++) z2[j] = zp[j];
    }

    float dvd = Dv[d];
    const char* ubase = (const char*)(u + ((size_t)b * SEQLEN + (size_t)c * TC) * HID
                                        + (size_t)dset * DBLK);
    float* po = out + ((size_t)b * SEQLEN + (size_t)c * TC) * HID + d;

    ISSUE_TILE(0, 0);
    __syncthreads();
    int cur = 0;
    for (int tile = 0; tile < NTILE; ++tile) {
        if (tile + 1 < NTILE) ISSUE_TILE(tile + 1, cur ^ 1);
        const float* ut = &utile[cur][w * 16 + dl];
        float* po_t = po + (size_t)tile * TT * HID;
        #pragma unroll
        for (int r0 = 0; r0 < TT; r0 += RB) {
            float ylane[RB], usv[RB];
            #pragma unroll
            for (int i = 0; i < RB; i++) {
                float uss = ut[(r0 + i) * DBLK];
                usv[i] = uss;
                f32x2 us; us.x = uss; us.y = uss;
                #pragma unroll
                for (int j = 0; j < NP; j++)
                    z2[j] = __builtin_elementwise_fma(a2[j], z2[j], us);
                f32x2 acc0 = z2[0] * w2[0];
                f32x2 acc1 = z2[1] * w2[1];
                #pragma unroll
                for (int j = 2; j < NP; j += 2) {
                    acc0 = __builtin_elementwise_fma(z2[j + 0], w2[j + 0], acc0);
                    acc1 = __builtin_elementwise_fma(z2[j + 1], w2[j + 1], acc1);
                }
                acc0 += acc1;
                ylane[i] = acc0.x + acc0.y;
            }
            #pragma unroll
            for (int i = 0; i < RB; i++) ylane[i] = quad_reduce_add(ylane[i]);
            #pragma unroll
            for (int i = 0; i < RB; i++)
                po_t[(size_t)(r0 + i) * HID] = fmaf(dvd, usv[i], ylane[i]);
        }
        __syncthreads();
        cur ^= 1;
    }
}

extern "C" void kernel_launch(void* const* d_in, const int* in_sizes, int n_in,
                              void* d_out, int out_size, void* d_ws, size_t ws_size,
                              hipStream_t stream) {
    const float* u  = (const float*)d_in[0];
    const float* A  = (const float*)d_in[1];
    const float* Bm = (const float*)d_in[2];
    const float* C  = (const float*)d_in[3];
    const float* Dv = (const float*)d_in[4];
    const float* dt = (const float*)d_in[5];
    float* out = (float*)d_out;

    char* ws = (char*)d_ws;
    float* pa  = (float*)(ws + WS_PA);
    float* pw  = (float*)(ws + WS_PW);
    float* pE  = (float*)(ws + WS_PE);
    float* pl2 = (float*)(ws + WS_PL2);
    float* zl  = (float*)(ws + WS_ZL);
    unsigned short* KRF = (unsigned short*)(ws + WS_KRF);
    unsigned short* W2F = (unsigned short*)(ws + WS_W2F);
    unsigned short* ZT  = (unsigned short*)(ws + WS_ZT);
    unsigned short* UBF = (unsigned short*)(ws + WS_UBF);

    bool mfma = (ws_size >= WS_NEED);

    k0_params<<<(HID * STATE) / 256, 256, 0, stream>>>(A, Bm, C, dt, pa, pw, pE, pl2);

    if (mfma) {
        k1_locals<<<16 * 8 * NC, 256, 0, stream>>>(u, pa, zl, UBF);
        // zl consumed here...
        k2_zt<<<(BATCH * HID * STATE) / 256, 256, 0, stream>>>(pE, zl, ZT);
        // ...then KRF may overwrite zl's region
        k_krf<<<1024, 256, 0, stream>>>(pw, pl2, Dv, KRF);
        k_w2f<<<1024, 256, 0, stream>>>(pw, pl2, W2F);
        k3_mfma<<<512, 1024, 0, stream>>>(UBF, KRF, W2F, ZT, out);
    } else {
        k1_locals<<<16 * 8 * (NC - 1), 256, 0, stream>>>(u, pa, zl, nullptr);
        k2_scan<<<(BATCH * HID * STATE) / 256, 256, 0, stream>>>(pE, zl);
        k3_scalar<<<16 * 8 * NC, 256, 0, stream>>>(u, Dv, pa, pw, zl, out);
    }
}

// Round 18
// 156.806 us; speedup vs baseline: 1.4996x; 1.0346x over previous
//
#include <hip/hip_runtime.h>
#include <math.h>

#define BATCH  8
#define SEQLEN 4096
#define HID    1024
#define STATE  64
#define NC     16
#define TC     (SEQLEN / NC)   // 256 steps per chunk
#define TT     32              // time rows per LDS tile (k1/scalar path)
#define NTILE  (TC / TT)
#define DBLK   64
#define NS     16
#define NP     8
#define RB     8

typedef float f32x2 __attribute__((ext_vector_type(2)));
typedef float f32x4 __attribute__((ext_vector_type(4)));
typedef short bf16x8 __attribute__((ext_vector_type(8)));
typedef unsigned int u32x4 __attribute__((ext_vector_type(4)));

// ws layout (bytes). KRF overlays zl — zl is dead after k2_zt, and k_krf
// launches AFTER k2_zt. No other overlaps (audited):
//   params [0,1M) | zl [1M,31M) | KRF [1M,17M) after-zl | W2F [31M,63M)
//   | ZT [63M,79M) | UBF [79M,143M)
#define WS_PA   0
#define WS_PW   (256 * 1024)
#define WS_PE   (512 * 1024)
#define WS_PL2  (768 * 1024)
#define WS_ZL   (1ull  * 1024 * 1024)   // f32 [15][8][1024][64] = 30 MB
#define WS_KRF  (1ull  * 1024 * 1024)   // ushort[1024][8192] = 16 MB (after zl dead)
#define WS_W2F  (31ull * 1024 * 1024)   // ushort[1024][16384] = 32 MB
#define WS_ZT   (63ull * 1024 * 1024)   // ushort[1024][128][64] = 16 MB
#define WS_UBF  (79ull * 1024 * 1024)   // [gbc128][tile8][d1024][64B] = 64 MB
#define WS_NEED (143ull * 1024 * 1024)

__device__ __forceinline__ unsigned int f2bf(float x) {
    unsigned int u = __builtin_bit_cast(unsigned int, x);
    u = (u + 0x7FFFu + ((u >> 16) & 1u)) >> 16;
    return u & 0xFFFFu;
}

__device__ __forceinline__ void gload_lds16(const void* g, void* l) {
    __builtin_amdgcn_global_load_lds((const __attribute__((address_space(1))) void*)g,
                                     (__attribute__((address_space(3))) void*)l,
                                     16, 0, 0);
}

__device__ __forceinline__ float quad_reduce_add(float y) {
    int t = __builtin_amdgcn_mov_dpp(__builtin_bit_cast(int, y), 0xB1, 0xF, 0xF, true);
    y += __builtin_bit_cast(float, t);
    t = __builtin_amdgcn_mov_dpp(__builtin_bit_cast(int, y), 0x4E, 0xF, 0xF, true);
    y += __builtin_bit_cast(float, t);
    return y;
}

// ---------------------------------------------------------------- K0: params
__global__ void k0_params(const float* __restrict__ A, const float* __restrict__ Bm,
                          const float* __restrict__ C, const float* __restrict__ dt,
                          float* __restrict__ pa, float* __restrict__ pw,
                          float* __restrict__ pE, float* __restrict__ pl2) {
    int i = blockIdx.x * 256 + threadIdx.x;
    if (i >= HID * STATE) return;
    int n = i & (STATE - 1);
    float aexp = expf(A[i]);
    float dtn  = dt[n];
    float a    = expf(-aexp * dtn);
    pa[i]  = a;
    pw[i]  = C[i] * (Bm[i] * (1.0f - a) / aexp);
    pE[i]  = expf(-aexp * dtn * (float)TC);
    pl2[i] = -aexp * dtn * 1.44269504088896340736f;   // log2(a)
}

// ------------------------------------------- K1: chunk-local end states + UBF emit
// UBF emit: direct per-lane 16B stores (wave covers a contiguous 1024B region;
// 4 lanes/64B-line merge in the coalescer). No LDS bounce, no extra barriers.
__global__ __launch_bounds__(256, 3) void k1_locals(const float* __restrict__ u,
                                                    const float* __restrict__ pa,
                                                    float* __restrict__ zl,
                                                    unsigned short* __restrict__ ubf) {
    __shared__ float utile[2][TT * DBLK];
    int bid  = blockIdx.x;
    int dset = bid & 15;
    int b    = (bid >> 4) & 7;
    int c    = bid >> 7;                       // chunk 0..15 (mfma) / 0..14 (fallback)
    int w    = threadIdx.x >> 6;
    int lane = threadIdx.x & 63;
    int dl   = lane >> 2, p = lane & 3;
    int d    = dset * DBLK + w * 16 + dl;

    f32x2 a2[NP], z2[NP];
    {
        const f32x2* pap = (const f32x2*)(pa + (size_t)d * STATE + p * NS);
        #pragma unroll
        for (int j = 0; j < NP; j++) a2[j] = pap[j];
    }
    #pragma unroll
    for (int j = 0; j < NP; j++) { z2[j].x = 0.f; z2[j].y = 0.f; }

    const char* ubase = (const char*)(u + ((size_t)b * SEQLEN + (size_t)c * TC) * HID
                                        + (size_t)dset * DBLK);

    #define ISSUE_TILE(t, buf)                                                        \
        {                                                                             \
            _Pragma("unroll")                                                         \
            for (int k = 0; k < 2; k++) {                                             \
                int off = w * 2048 + k * 1024 + lane * 16;                            \
                int row = off >> 8;                                                   \
                int col = off & 255;                                                  \
                const float* src = (const float*)(ubase + ((size_t)((t) * TT + row)) * (HID * 4) + col); \
                float* dst = &utile[buf][w * 512 + k * 256];                           \
                gload_lds16(src, dst);                                                \
            }                                                                         \
        }

    ISSUE_TILE(0, 0);
    __syncthreads();
    int cur = 0;
    for (int tile = 0; tile < NTILE; ++tile) {
        if (tile + 1 < NTILE) ISSUE_TILE(tile + 1, cur ^ 1);
        const float* ut = &utile[cur][w * 16 + dl];
        #pragma unroll
        for (int r = 0; r < TT; r++) {
            float uss = ut[r * DBLK];
            f32x2 us; us.x = uss; us.y = uss;
            #pragma unroll
            for (int j = 0; j < NP; j++)
                z2[j] = __builtin_elementwise_fma(a2[j], z2[j], us);
        }
        if (ubf != nullptr) {
            // lane packs 8 t-rows of its column -> 16B, stored straight to UBF
            int cw   = w * 16 + (lane & 15);
            int tgrp = lane >> 4;
            const float* colp = &utile[cur][cw];
            unsigned int pk[4];
            #pragma unroll
            for (int q = 0; q < 4; q++) {
                int r0 = tgrp * 8 + 2 * q;
                pk[q] = f2bf(colp[r0 * DBLK]) | (f2bf(colp[(r0 + 1) * DBLK]) << 16);
            }
            unsigned short* dstg = ubf
                + (((size_t)(b * 16 + c) * 8 + tile) * 1024 + dset * 64 + cw) * 32
                + tgrp * 8;
            *(u32x4*)dstg = (u32x4){pk[0], pk[1], pk[2], pk[3]};
        }
        __syncthreads();
        cur ^= 1;
    }

    if (c < NC - 1) {
        f32x2* zp = (f32x2*)(zl + (((size_t)c * BATCH + b) * HID + d) * STATE + p * NS);
        #pragma unroll
        for (int j = 0; j < NP; j++) zp[j] = z2[j];
    }
}

// ---------------------------------- K2 (fallback): prefix scan in-place in zl
__global__ void k2_scan(const float* __restrict__ pE, float* __restrict__ zl) {
    int i  = blockIdx.x * 256 + threadIdx.x;
    int dn = i & (HID * STATE - 1);
    float E = pE[dn];
    size_t stride = (size_t)BATCH * HID * STATE;
    float g = zl[i];
    for (int c = 1; c < NC - 1; c++) {
        float v = zl[i + c * stride];
        g = fmaf(E, g, v);
        zl[i + c * stride] = g;
    }
}

// ---------------------------------- K2-ZT (mfma): scan + emit bf16 chunk-inits
__global__ void k2_zt(const float* __restrict__ pE, const float* __restrict__ zl,
                      unsigned short* __restrict__ ZT) {
    int i = blockIdx.x * 256 + threadIdx.x;     // b*65536 + d*64 + n
    int n = i & 63;
    int d = (i >> 6) & 1023;
    int b = i >> 16;
    float E = pE[d * 64 + n];
    size_t stride = (size_t)BATCH * HID * STATE;
    unsigned short* zt = ZT + (size_t)d * 8192 + (size_t)b * 1024 + n;
    zt[0] = 0;
    float g = zl[i];
    zt[64] = (unsigned short)f2bf(g);
    for (int c = 2; c < 16; c++) {
        g = fmaf(E, g, zl[i + (size_t)(c - 1) * stride]);
        zt[(size_t)c * 64] = (unsigned short)f2bf(g);
    }
}

// ---------------------------------- kKRF: fragment-major conv-kernel table
// (launched AFTER k2_zt: overlays the then-dead zl region)
__global__ void k_krf(const float* __restrict__ pw, const float* __restrict__ pl2,
                      const float* __restrict__ Dv, unsigned short* __restrict__ KRF) {
    __shared__ float wv[64], e2[64], K[256];
    int d = blockIdx.x, t = threadIdx.x;
    if (t < 64) { wv[t] = pw[d * 64 + t]; e2[t] = pl2[d * 64 + t]; }
    __syncthreads();
    float s = 0.0f;
    for (int n = 0; n < 64; n++) s += wv[n] * exp2f((float)t * e2[n]);
    if (t == 0) s += Dv[d];
    K[t] = s;
    __syncthreads();
    for (int idx = t; idx < 8192; idx += 256) {
        int j  = idx & 7;
        int ll = (idx >> 3) & 63;
        int m  = idx >> 9;
        int x  = (ll & 15) - 8 * (ll >> 4) + 16 * m - j;
        unsigned short v = 0;
        if (x >= 0) v = (unsigned short)f2bf(K[x]);
        KRF[(size_t)d * 8192 + idx] = v;
    }
}

// ---------------------------------- kW2F: fragment-major state-correction table
__global__ void k_w2f(const float* __restrict__ pw, const float* __restrict__ pl2,
                      unsigned short* __restrict__ W2F) {
    __shared__ float wv[64], e2[64];
    int d = blockIdx.x, t = threadIdx.x;
    if (t < 64) { wv[t] = pw[d * 64 + t]; e2[t] = pl2[d * 64 + t]; }
    __syncthreads();
    for (int idx = t; idx < 16384; idx += 256) {
        int j  = idx & 7;
        int ll = (idx >> 3) & 63;
        int ns = (idx >> 9) & 1;
        int tt = idx >> 10;
        int n  = ns * 32 + 8 * (ll >> 4) + j;
        int tg = tt * 16 + (ll & 15);
        float val = wv[n] * exp2f((float)(tg + 1) * e2[n]);
        W2F[(size_t)d * 16384 + idx] = (unsigned short)f2bf(val);
    }
}

// ---------------------------------- K3 MFMA: 128KB tile from UBF, 1 wave = 1 d
__global__ __launch_bounds__(1024, 1) void k3_mfma(const unsigned short* __restrict__ ubf,
                                                   const unsigned short* __restrict__ KRF,
                                                   const unsigned short* __restrict__ W2F,
                                                   const unsigned short* __restrict__ ZT,
                                                   float* __restrict__ out) {
    __shared__ __align__(16) char smem[131072];   // [dl16][bc16][32 slots x 16B]
    int bid = blockIdx.x;
    int dg  = bid & 63;          // xcd = bid%8 = dg%8 -> same-dg blocks share one L2
    int bcg = bid >> 6;          // 0..7
    int tid = threadIdx.x;
    int w   = tid >> 6;          // wave 0..15, owns d = dg*16 + w (stages dloc = w)
    int l   = tid & 63;
    int g   = l >> 4, r16 = l & 15;
    int d   = dg * 16 + w;

    // ---- stage: global_load_lds from UBF, source-side slot pre-swizzle
    {
        int h = l >> 5, q = l & 31;
        #pragma unroll
        for (int i = 0; i < 8; i++) {
            int bc = 2 * i + h;
            int sc = (q - 5 * bc - 3 * w) & 31;
            int gbc = bcg * 16 + bc;
            const char* src = (const char*)ubf
                + (((size_t)(gbc * 8 + (sc >> 2)) * 1024) + dg * 16 + w) * 64
                + (sc & 3) * 16;
            char* dst = &smem[(unsigned)(w * 16 + 2 * i) * 512];
            gload_lds16(src, dst);
        }
    }
    __syncthreads();

    f32x4 acc[16];
    #pragma unroll
    for (int tt = 0; tt < 16; tt++) acc[tt] = (f32x4){0.f, 0.f, 0.f, 0.f};

    const unsigned short* krf = KRF + (size_t)d * 8192 + l * 8;
    unsigned int rowr = (unsigned int)(w * 16 + r16) * 512;
    int rot = (5 * r16 + 3 * w) & 31;

    // ---- conv core, half 1: m = 0..7 (verified r14 structure)
    {
        bf16x8 Af[8];
        #pragma unroll
        for (int mm = 0; mm < 8; mm++)
            Af[mm] = *(const bf16x8*)(krf + (size_t)mm * 512);
        #pragma unroll
        for (int mm = 0; mm < 8; mm++) {
            #pragma unroll
            for (int sk = 0; sk < 8; sk++) {
                if (2 * sk + mm <= 15) {
                    int slot = ((sk * 4 + g) + rot) & 31;
                    bf16x8 B = *(const bf16x8*)(&smem[rowr + slot * 16]);
                    acc[2 * sk + mm] =
                        __builtin_amdgcn_mfma_f32_16x16x32_bf16(Af[mm], B, acc[2 * sk + mm], 0, 0, 0);
                }
            }
        }
    }
    __builtin_amdgcn_sched_barrier(0);
    // ---- conv core, half 2: m = 8..15
    {
        bf16x8 Af[8];
        #pragma unroll
        for (int mm = 0; mm < 8; mm++)
            Af[mm] = *(const bf16x8*)(krf + (size_t)(8 + mm) * 512);
        #pragma unroll
        for (int mm = 0; mm < 8; mm++) {
            #pragma unroll
            for (int sk = 0; sk < 4; sk++) {
                if (2 * sk + 8 + mm <= 15) {
                    int slot = ((sk * 4 + g) + rot) & 31;
                    bf16x8 B = *(const bf16x8*)(&smem[rowr + slot * 16]);
                    acc[2 * sk + 8 + mm] =
                        __builtin_amdgcn_mfma_f32_16x16x32_bf16(Af[mm], B, acc[2 * sk + 8 + mm], 0, 0, 0);
                }
            }
        }
    }
    __builtin_amdgcn_sched_barrier(0);

    // ---- state-init correction: acc[tt] += W2F(tt,ns) x ZT(bc,n)
    {
        const unsigned short* ztd = ZT + (size_t)d * 8192 + (size_t)bcg * 1024;
        bf16x8 Bz0 = *(const bf16x8*)(ztd + (size_t)r16 * 64 + 0 * 32 + 8 * g);
        bf16x8 Bz1 = *(const bf16x8*)(ztd + (size_t)r16 * 64 + 1 * 32 + 8 * g);
        const unsigned short* w2f = W2F + (size_t)d * 16384 + l * 8;
        #pragma unroll
        for (int grp = 0; grp < 4; grp++) {
            bf16x8 Aw[8];
            #pragma unroll
            for (int q = 0; q < 8; q++) {
                int tt = grp * 4 + (q >> 1);
                int ns = q & 1;
                Aw[q] = *(const bf16x8*)(w2f + (size_t)(tt * 2 + ns) * 512);
            }
            #pragma unroll
            for (int q = 0; q < 8; q++) {
                int tt = grp * 4 + (q >> 1);
                acc[tt] = __builtin_amdgcn_mfma_f32_16x16x32_bf16(Aw[q], (q & 1) ? Bz1 : Bz0,
                                                                  acc[tt], 0, 0, 0);
            }
            __builtin_amdgcn_sched_barrier(0);
        }
    }

    // ---- epilogue: padded LDS transpose -> full 64B-line stores (r14 verified)
    float* eps = (float*)smem;
    int p = tid >> 2, sub = tid & 3;
    int t16r = p >> 4, bcr = p & 15;
    int gbcr = bcg * 16 + bcr;
    int bo = gbcr >> 4, co = gbcr & 15;
    float* pout = out + ((size_t)(bo * SEQLEN + co * TC + t16r)) * HID + dg * 16 + sub * 4;
    #pragma unroll
    for (int tt = 0; tt < 16; tt++) {
        __syncthreads();
        #pragma unroll
        for (int rr = 0; rr < 4; rr++)
            eps[((g * 4 + rr) * 16 + r16) * 21 + w] = acc[tt][rr];
        __syncthreads();
        f32x4 vv;
        #pragma unroll
        for (int j = 0; j < 4; j++) vv[j] = eps[p * 21 + sub * 4 + j];
        *(f32x4*)(pout + (size_t)(tt * 16) * HID) = vv;
    }
}

// ---------------------------------- fallback scalar K3 (round-10 best, 118 us)
__global__ __launch_bounds__(256, 3) void k3_scalar(const float* __restrict__ u,
                                                    const float* __restrict__ Dv,
                                                    const float* __restrict__ pa,
                                                    const float* __restrict__ pw,
                                                    const float* __restrict__ zl,
                                                    float* __restrict__ out) {
    __shared__ float utile[2][TT * DBLK];
    int bid  = blockIdx.x;
    int dset = bid & 15;
    int b    = (bid >> 4) & 7;
    int c    = bid >> 7;
    int w    = threadIdx.x >> 6;
    int lane = threadIdx.x & 63;
    int dl   = lane >> 2, p = lane & 3;
    int d    = dset * DBLK + w * 16 + dl;

    f32x2 a2[NP], w2[NP], z2[NP];
    {
        const f32x2* pap = (const f32x2*)(pa + (size_t)d * STATE + p * NS);
        const f32x2* pwp = (const f32x2*)(pw + (size_t)d * STATE + p * NS);
        #pragma unroll
        for (int j = 0; j < NP; j++) { a2[j] = pap[j]; w2[j] = pwp[j]; }
    }
    if (c == 0) {
        #pragma unroll
        for (int j = 0; j < NP; j++) { z2[j].x = 0.f; z2[j].y = 0.f; }
    } else {
        size_t stride = (size_t)BATCH * HID * STATE;
        const f32x2* zp = (const f32x2*)(zl + (size_t)(c - 1) * stride +
                                         ((size_t)b * HID + d) * STATE + p * NS);
        #pragma unroll
        for (int j = 0; j < NP; j++) z2[j] = zp[j];
    }

    float dvd = Dv[d];
    const char* ubase = (const char*)(u + ((size_t)b * SEQLEN + (size_t)c * TC) * HID
                                        + (size_t)dset * DBLK);
    float* po = out + ((size_t)b * SEQLEN + (size_t)c * TC) * HID + d;

    ISSUE_TILE(0, 0);
    __syncthreads();
    int cur = 0;
    for (int tile = 0; tile < NTILE; ++tile) {
        if (tile + 1 < NTILE) ISSUE_TILE(tile + 1, cur ^ 1);
        const float* ut = &utile[cur][w * 16 + dl];
        float* po_t = po + (size_t)tile * TT * HID;
        #pragma unroll
        for (int r0 = 0; r0 < TT; r0 += RB) {
            float ylane[RB], usv[RB];
            #pragma unroll
            for (int i = 0; i < RB; i++) {
                float uss = ut[(r0 + i) * DBLK];
                usv[i] = uss;
                f32x2 us; us.x = uss; us.y = uss;
                #pragma unroll
                for (int j = 0; j < NP; j++)
                    z2[j] = __builtin_elementwise_fma(a2[j], z2[j], us);
                f32x2 acc0 = z2[0] * w2[0];
                f32x2 acc1 = z2[1] * w2[1];
                #pragma unroll
                for (int j = 2; j < NP; j += 2) {
                    acc0 = __builtin_elementwise_fma(z2[j + 0], w2[j + 0], acc0);
                    acc1 = __builtin_elementwise_fma(z2[j + 1], w2[j + 1], acc1);
                }
                acc0 += acc1;
                ylane[i] = acc0.x + acc0.y;
            }
            #pragma unroll
            for (int i = 0; i < RB; i++) ylane[i] = quad_reduce_add(ylane[i]);
            #pragma unroll
            for (int i = 0; i < RB; i++)
                po_t[(size_t)(r0 + i) * HID] = fmaf(dvd, usv[i], ylane[i]);
        }
        __syncthreads();
        cur ^= 1;
    }
}

extern "C" void kernel_launch(void* const* d_in, const int* in_sizes, int n_in,
                              void* d_out, int out_size, void* d_ws, size_t ws_size,
                              hipStream_t stream) {
    const float* u  = (const float*)d_in[0];
    const float* A  = (const float*)d_in[1];
    const float* Bm = (const float*)d_in[2];
    const float* C  = (const float*)d_in[3];
    const float* Dv = (const float*)d_in[4];
    const float* dt = (const float*)d_in[5];
    float* out = (float*)d_out;

    char* ws = (char*)d_ws;
    float* pa  = (float*)(ws + WS_PA);
    float* pw  = (float*)(ws + WS_PW);
    float* pE  = (float*)(ws + WS_PE);
    float* pl2 = (float*)(ws + WS_PL2);
    float* zl  = (float*)(ws + WS_ZL);
    unsigned short* KRF = (unsigned short*)(ws + WS_KRF);
    unsigned short* W2F = (unsigned short*)(ws + WS_W2F);
    unsigned short* ZT  = (unsigned short*)(ws + WS_ZT);
    unsigned short* UBF = (unsigned short*)(ws + WS_UBF);

    bool mfma = (ws_size >= WS_NEED);

    k0_params<<<(HID * STATE) / 256, 256, 0, stream>>>(A, Bm, C, dt, pa, pw, pE, pl2);

    if (mfma) {
        k1_locals<<<16 * 8 * NC, 256, 0, stream>>>(u, pa, zl, UBF);
        // zl consumed here...
        k2_zt<<<(BATCH * HID * STATE) / 256, 256, 0, stream>>>(pE, zl, ZT);
        // ...then KRF may overwrite zl's region
        k_krf<<<1024, 256, 0, stream>>>(pw, pl2, Dv, KRF);
        k_w2f<<<1024, 256, 0, stream>>>(pw, pl2, W2F);
        k3_mfma<<<512, 1024, 0, stream>>>(UBF, KRF, W2F, ZT, out);
    } else {
        k1_locals<<<16 * 8 * (NC - 1), 256, 0, stream>>>(u, pa, zl, nullptr);
        k2_scan<<<(BATCH * HID * STATE) / 256, 256, 0, stream>>>(pE, zl);
        k3_scalar<<<16 * 8 * NC, 256, 0, stream>>>(u, Dv, pa, pw, zl, out);
    }
}